// Round 5
// baseline (16839.705 us; speedup 1.0000x reference)
//
#include <hip/hip_runtime.h>
#include <hip/hip_bf16.h>

#define VSZ 128
#define EMBD 64
#define HSZ 512
#define BSZ 256
#define TLEN 512
#define NBLK 72              // 16 P + 16 L0 + 16 L1a + 16 L1b + 8 FC

typedef __attribute__((ext_vector_type(8))) short short8;
typedef __attribute__((ext_vector_type(4))) float f32x4;
typedef __attribute__((ext_vector_type(4))) unsigned int u32x4;
typedef __hip_bfloat16 bf16;

#define SQ   ((size_t)HSZ*HSZ)

// ---- weight region (bf16 element offsets) ----
#define O_WHH0HI ((size_t)0)
#define O_WHH0LO (O_WHH0HI + SQ)
#define O_WIH1HI (O_WHH0LO + SQ)
#define O_WIH1LO (O_WIH1HI + SQ)
#define O_WHH1HI (O_WIH1LO + SQ)
#define O_WHH1LO (O_WHH1HI + SQ)
#define O_WIH0HI (O_WHH1LO + SQ)                 // [N=512][K=64]
#define O_WIH0LO (O_WIH0HI + (size_t)HSZ*EMBD)
#define O_WFCHI  (O_WIH0LO + (size_t)HSZ*EMBD)   // [N=128][K=512]
#define O_WFCLO  (O_WFCHI + (size_t)VSZ*HSZ)
#define O_EMBHI  (O_WFCLO + (size_t)VSZ*HSZ)     // [128][64]
#define O_EMBLO  (O_EMBHI + (size_t)VSZ*EMBD)
// weights end at byte 3,571,712

// ---- ring / counter region (byte offsets) ----
#define O_RINGB  ((size_t)3571712)
#define O_ERING  (O_RINGB)                        // fp32 [16 grp][2 slot][8192] lane-major
#define O_H0RING (O_RINGB + ((size_t)1<<20))      // u32  [16][2][8192] row-major packed hi|lo
#define O_ZRING  (O_RINGB + ((size_t)2<<20))      // fp32 lane-major
#define O_H1RING (O_RINGB + ((size_t)3<<20))      // u32 row-major packed
#define O_CTRB   (O_RINGB + ((size_t)4<<20))      // PROD[72] + CONS[72], 256B apart each

#define CTR_STRIDE 64        // ints (256B) per counter
#define SLOTW 8192           // 4B elems per slot
#define GRPW  16384          // 2 slots
#define ASTR  1024           // A-plane row stride bytes (swizzled, no pad)
#define APLANE 16384         // 16 rows
#define SMEMSZ 65536

static __device__ __forceinline__ short8 ld8(const bf16* p) { return *(const short8*)p; }
static __device__ __forceinline__ float b2f(bf16 v) { return __bfloat162float(v); }
#define MFMA(a,b,c) __builtin_amdgcn_mfma_f32_16x16x32_bf16((a),(b),(c),0,0,0)

// ---- device-scope primitives: ALL loads wait inside the asm block ----
static __device__ __forceinline__ void st4_sc(void* p, unsigned v) {
    asm volatile("global_store_dword %0, %1, off sc0 sc1" :: "v"(p), "v"(v) : "memory");
}
static __device__ __forceinline__ void st4i(int* p, int v) { st4_sc(p, (unsigned)v); }
static __device__ __forceinline__ void st16sc(float* p, const f32x4* v) {
    asm volatile(
        "global_store_dwordx4 %0, %1, off sc0 sc1\n\t"
        "global_store_dwordx4 %0, %2, off offset:16 sc0 sc1\n\t"
        "global_store_dwordx4 %0, %3, off offset:32 sc0 sc1\n\t"
        "global_store_dwordx4 %0, %4, off offset:48 sc0 sc1"
        :: "v"(p), "v"(v[0]), "v"(v[1]), "v"(v[2]), "v"(v[3]) : "memory");
}
static __device__ __forceinline__ void ld64sc(const float* p, f32x4* v) {
    asm volatile(
        "global_load_dwordx4 %0, %4, off sc0 sc1\n\t"
        "global_load_dwordx4 %1, %4, off offset:16 sc0 sc1\n\t"
        "global_load_dwordx4 %2, %4, off offset:32 sc0 sc1\n\t"
        "global_load_dwordx4 %3, %4, off offset:48 sc0 sc1\n\t"
        "s_waitcnt vmcnt(0)"
        : "=&v"(v[0]), "=&v"(v[1]), "=&v"(v[2]), "=&v"(v[3])
        : "v"(p) : "memory");
}
static __device__ __forceinline__ void pref4sc(const unsigned* base, int tid, u32x4* v) {
    const unsigned* p0 = base + 0*2048 + tid*4;
    const unsigned* p1 = base + 1*2048 + tid*4;
    const unsigned* p2 = base + 2*2048 + tid*4;
    const unsigned* p3 = base + 3*2048 + tid*4;
    asm volatile(
        "global_load_dwordx4 %0, %4, off sc0 sc1\n\t"
        "global_load_dwordx4 %1, %5, off sc0 sc1\n\t"
        "global_load_dwordx4 %2, %6, off sc0 sc1\n\t"
        "global_load_dwordx4 %3, %7, off sc0 sc1\n\t"
        "s_waitcnt vmcnt(0)"
        : "=&v"(v[0]), "=&v"(v[1]), "=&v"(v[2]), "=&v"(v[3])
        : "v"(p0), "v"(p1), "v"(p2), "v"(p3) : "memory");
}
static __device__ __forceinline__ void pref8sc(const unsigned* b1, const unsigned* b2,
                                               int tid, u32x4* v) {
    const unsigned* q0 = b1 + 0*2048 + tid*4; const unsigned* q1 = b1 + 1*2048 + tid*4;
    const unsigned* q2 = b1 + 2*2048 + tid*4; const unsigned* q3 = b1 + 3*2048 + tid*4;
    const unsigned* q4 = b2 + 0*2048 + tid*4; const unsigned* q5 = b2 + 1*2048 + tid*4;
    const unsigned* q6 = b2 + 2*2048 + tid*4; const unsigned* q7 = b2 + 3*2048 + tid*4;
    asm volatile(
        "global_load_dwordx4 %0, %8, off sc0 sc1\n\t"
        "global_load_dwordx4 %1, %9, off sc0 sc1\n\t"
        "global_load_dwordx4 %2, %10, off sc0 sc1\n\t"
        "global_load_dwordx4 %3, %11, off sc0 sc1\n\t"
        "global_load_dwordx4 %4, %12, off sc0 sc1\n\t"
        "global_load_dwordx4 %5, %13, off sc0 sc1\n\t"
        "global_load_dwordx4 %6, %14, off sc0 sc1\n\t"
        "global_load_dwordx4 %7, %15, off sc0 sc1\n\t"
        "s_waitcnt vmcnt(0)"
        : "=&v"(v[0]), "=&v"(v[1]), "=&v"(v[2]), "=&v"(v[3]),
          "=&v"(v[4]), "=&v"(v[5]), "=&v"(v[6]), "=&v"(v[7])
        : "v"(q0), "v"(q1), "v"(q2), "v"(q3), "v"(q4), "v"(q5), "v"(q6), "v"(q7)
        : "memory");
}
// ONE lane-parallel poll: lane0 checks (pa>=na), lane1 checks (pb>=nb); single RT when hit
static __device__ __forceinline__ void poll2(const int* pa, int na,
                                             const int* pb, int nb,
                                             int lane, int wv) {
    if (wv == 0) {
        const int* p = (lane & 1) ? pb : pa;
        int need     = (lane & 1) ? nb : na;
        bool act = (lane < 2);
        for (int it = 0; it < (1 << 17); ++it) {
            int ok = 1;
            if (act) {
                int v;
                asm volatile("global_load_dword %0, %1, off sc0 sc1\n\t"
                             "s_waitcnt vmcnt(0)" : "=v"(v) : "v"(p) : "memory");
                ok = (v >= need);
            }
            if (__all(ok)) break;
            __builtin_amdgcn_s_sleep(2);
        }
    }
    __syncthreads();
}
// unpack u32(hi | lo<<16) row-major slot data into swizzled hi/lo A-planes
static __device__ __forceinline__ void awrite4(char* Ahi, char* Alo, int tid,
                                               const u32x4* v, int rowoff) {
    const int colb8 = (tid & 127) * 8;
#pragma unroll
    for (int j = 0; j < 4; j++) {
        int row = rowoff + j*4 + (tid >> 7);
        int off = row * ASTR + (colb8 ^ ((row & 7) << 4));
        unsigned a = v[j][0], b = v[j][1], c = v[j][2], d = v[j][3];
        uint2 hi, lo;
        hi.x = (a & 0xffffu) | (b << 16);  hi.y = (c & 0xffffu) | (d << 16);
        lo.x = (a >> 16) | (b & 0xffff0000u); lo.y = (c >> 16) | (d & 0xffff0000u);
        *(uint2*)(Ahi + off) = hi;
        *(uint2*)(Alo + off) = lo;
    }
}
// K=512 hi/lo-split MFMA loop with register double-buffered B stream
static __device__ __forceinline__ void kloop512(const char* Ahi, const char* Alo,
                                                const bf16* Whi, const bf16* Wlo,
                                                int l15, int quad, int colbase,
                                                f32x4 accA[4], f32x4 accB[4]) {
    const int swz = (l15 & 7) << 4;
    const int arow = l15 * ASTR;
    const bf16* wh[4]; const bf16* wl[4];
#pragma unroll
    for (int ni = 0; ni < 4; ni++) {
        int c = colbase + ni*16 + l15;
        wh[ni] = Whi + (size_t)c * HSZ + quad*8;
        wl[ni] = Wlo + (size_t)c * HSZ + quad*8;
    }
    short8 bh[2][4], bl[2][4];
#pragma unroll
    for (int ni = 0; ni < 4; ni++) { bh[0][ni] = ld8(wh[ni]); bl[0][ni] = ld8(wl[ni]); }
#pragma unroll
    for (int kc = 0; kc < 16; kc++) {
        const int cb = kc & 1, nb2 = cb ^ 1;
        if (kc < 15) {
#pragma unroll
            for (int ni = 0; ni < 4; ni++) {
                bh[nb2][ni] = ld8(wh[ni] + (kc+1)*32);
                bl[nb2][ni] = ld8(wl[ni] + (kc+1)*32);
            }
        }
        const int aoff = arow + ((kc*64 + quad*16) ^ swz);
        short8 ah = *(const short8*)(Ahi + aoff);
        short8 al = *(const short8*)(Alo + aoff);
#pragma unroll
        for (int ni = 0; ni < 4; ni++) {
            accA[ni] = MFMA(ah, bh[cb][ni], accA[ni]);
            accB[ni] = MFMA(al, bh[cb][ni], accB[ni]);
            accB[ni] = MFMA(ah, bl[cb][ni], accB[ni]);
        }
    }
}

// ---- prep: split/transpose weights + zero counters ----
__global__ void k_prep(const float* __restrict__ emb, const float* __restrict__ Wih0,
                       const float* __restrict__ Whh0, const float* __restrict__ Wih1,
                       const float* __restrict__ Whh1, const float* __restrict__ Wfc,
                       bf16* __restrict__ ws) {
    int j = blockIdx.x * blockDim.x + threadIdx.x;
    const int SQi = HSZ * HSZ;
    if (j < SQi) {
        int n = j / HSZ, k = j - n * HSZ;
        float w = Whh0[k * HSZ + n];
        bf16 hi = __float2bfloat16(w);
        ws[O_WHH0HI + j] = hi; ws[O_WHH0LO + j] = __float2bfloat16(w - b2f(hi));
        return;
    }
    j -= SQi;
    if (j < SQi) {
        int n = j / HSZ, k = j - n * HSZ;
        float w = Wih1[k * HSZ + n];
        bf16 hi = __float2bfloat16(w);
        ws[O_WIH1HI + j] = hi; ws[O_WIH1LO + j] = __float2bfloat16(w - b2f(hi));
        return;
    }
    j -= SQi;
    if (j < SQi) {
        int n = j / HSZ, k = j - n * HSZ;
        float w = Whh1[k * HSZ + n];
        bf16 hi = __float2bfloat16(w);
        ws[O_WHH1HI + j] = hi; ws[O_WHH1LO + j] = __float2bfloat16(w - b2f(hi));
        return;
    }
    j -= SQi;
    if (j < HSZ * EMBD) {
        int n = j / EMBD, k = j - n * EMBD;
        float w = Wih0[k * HSZ + n];
        bf16 hi = __float2bfloat16(w);
        ws[O_WIH0HI + j] = hi; ws[O_WIH0LO + j] = __float2bfloat16(w - b2f(hi));
        return;
    }
    j -= HSZ * EMBD;
    if (j < VSZ * HSZ) {
        int n = j / HSZ, k = j - n * HSZ;
        float w = Wfc[k * VSZ + n];
        bf16 hi = __float2bfloat16(w);
        ws[O_WFCHI + j] = hi; ws[O_WFCLO + j] = __float2bfloat16(w - b2f(hi));
        return;
    }
    j -= VSZ * HSZ;
    if (j < VSZ * EMBD) {
        float w = emb[j];
        bf16 hi = __float2bfloat16(w);
        ws[O_EMBHI + j] = hi; ws[O_EMBLO + j] = __float2bfloat16(w - b2f(hi));
        return;
    }
    j -= VSZ * EMBD;
    if (j < NBLK * CTR_STRIDE * 2) ((int*)((char*)ws + O_CTRB))[j] = 0;
}

// ---- persistent 5-stage pipeline, depth-2 rings, single poll point per step ----
__global__ __launch_bounds__(512, 1) void k_persist(
    const int* __restrict__ x,
    const float* __restrict__ bih0, const float* __restrict__ bhh0,
    const float* __restrict__ bih1, const float* __restrict__ bhh1,
    const float* __restrict__ bfc,
    bf16* __restrict__ ws, float* __restrict__ out)
{
    extern __shared__ char smem[];
    const int tid = (int)threadIdx.x;
    const int lane = tid & 63;
    const int wv   = tid >> 6;
    const int l15  = lane & 15;
    const int quad = lane >> 4;
    const int bid  = (int)blockIdx.x;

    int* CTR = (int*)((char*)ws + O_CTRB);
#define PRODP(i) (CTR + (size_t)(i) * CTR_STRIDE)
#define CONSP(i) (CTR + (size_t)(NBLK + (i)) * CTR_STRIDE)

    if (bid < 16) {
        // ============ stage P: E[t] = emb[x[:,t]] @ Wih0 + bih0 + bhh0 ============
        const int r = bid, mb = r * 16;
        const bf16* WThi = ws + O_WIH0HI; const bf16* WTlo = ws + O_WIH0LO;
        const bf16* embhi = ws + O_EMBHI; const bf16* emblo = ws + O_EMBLO;
        char* Ahi = smem; char* Alo = smem + APLANE;
        int*  xbuf = (int*)(smem + 2 * APLANE);
        int* myprod = PRODP(r);
        const int* ccons = CONSP(16 + r);
        const int colbase = wv * 64;
        float bias[4];
#pragma unroll
        for (int ni = 0; ni < 4; ni++) { int c = colbase + ni*16 + l15; bias[ni] = bih0[c] + bhh0[c]; }
        float* ering = (float*)((char*)ws + O_ERING) + (size_t)r * GRPW;

        for (int t = 0; t < TLEN; ++t) {
            if (tid < 16) xbuf[tid] = x[(size_t)(mb + tid) * TLEN + t];
            __syncthreads();
            if (tid < 128) {                               // build swizzled A-planes
                int row = tid >> 3, oct = tid & 7;
                int xr = xbuf[row];
                int off = row * ASTR + ((oct * 16) ^ ((row & 7) << 4));
                *(short8*)(Ahi + off) = ld8(embhi + (size_t)xr * EMBD + oct * 8);
                *(short8*)(Alo + off) = ld8(emblo + (size_t)xr * EMBD + oct * 8);
            }
            __syncthreads();
            const int swz = (l15 & 7) << 4;
            f32x4 accA[4] = {}, accB[4] = {};
#pragma unroll
            for (int kc = 0; kc < 2; kc++) {
                int aoff = l15 * ASTR + ((kc*64 + quad*16) ^ swz);
                short8 ah = *(const short8*)(Ahi + aoff);
                short8 al = *(const short8*)(Alo + aoff);
#pragma unroll
                for (int ni = 0; ni < 4; ni++) {
                    int c = colbase + ni*16 + l15;
                    short8 bh = ld8(WThi + (size_t)c * EMBD + kc*32 + quad*8);
                    short8 bl = ld8(WTlo + (size_t)c * EMBD + kc*32 + quad*8);
                    accA[ni] = MFMA(ah, bh, accA[ni]);
                    accB[ni] = MFMA(al, bh, accB[ni]);
                    accB[ni] = MFMA(ah, bl, accB[ni]);
                }
            }
            if (t >= 2) poll2(ccons, t - 1, ccons, t - 1, lane, wv);  // E-slot reuse guard
            f32x4 ev[4];
#pragma unroll
            for (int ni = 0; ni < 4; ni++)
#pragma unroll
                for (int rr = 0; rr < 4; rr++) ev[ni][rr] = accA[ni][rr] + accB[ni][rr] + bias[ni];
            st16sc(ering + (size_t)(t & 1) * SLOTW + tid * 16, ev);
            asm volatile("s_waitcnt vmcnt(0)" ::: "memory");
            __syncthreads();
            if (tid == 0) st4i(myprod, t + 1);
        }

    } else if (bid < 32) {
        // ===== stage L0: h0[t] = tanh(E[t] + h0[t-1]@Whh0); state in LDS dbuf =====
        const int r = bid - 16;
        const bf16* Whi = ws + O_WHH0HI; const bf16* Wlo = ws + O_WHH0LO;
        char* A0 = smem;
        int* myprod = PRODP(16 + r);
        int* mycons = CONSP(16 + r);
        const int* pprod = PRODP(r);            // P
        const int* ccons = CONSP(32 + r);       // L1a consumed
        const float* ering = (const float*)((char*)ws + O_ERING) + (size_t)r * GRPW;
        unsigned* h0ring = (unsigned*)((char*)ws + O_H0RING) + (size_t)r * GRPW;
        const int colbase = wv * 64;

        for (int i = tid * 4; i < 2 * APLANE; i += 512 * 4) *(unsigned*)(A0 + i) = 0u;
        __syncthreads();

        for (int t = 0; t < TLEN; ++t) {
            const int cur = t & 1;
            const char* Ahi = A0 + (cur*2 + 0) * APLANE;
            const char* Alo = A0 + (cur*2 + 1) * APLANE;
            char* AhiN = A0 + ((cur^1)*2 + 0) * APLANE;
            char* AloN = A0 + ((cur^1)*2 + 1) * APLANE;
            f32x4 accA[4] = {}, accB[4] = {};
            kloop512(Ahi, Alo, Whi, Wlo, l15, quad, colbase, accA, accB);
            // ONE poll: E[t] ready AND L1a released h0 slot (t-2)
            poll2(pprod, t + 1, ccons, t - 1, lane, wv);
            f32x4 ec[4];
            ld64sc(ering + (size_t)(t & 1) * SLOTW + tid * 16, ec);
            unsigned* slot = h0ring + (size_t)(t & 1) * SLOTW;
#pragma unroll
            for (int ni = 0; ni < 4; ni++) {
                int c = colbase + ni*16 + l15;
#pragma unroll
                for (int rr = 0; rr < 4; rr++) {
                    int row = quad*4 + rr;
                    float v = tanhf(accA[ni][rr] + accB[ni][rr] + ec[ni][rr]);
                    bf16 hb = __float2bfloat16(v);
                    bf16 lb = __float2bfloat16(v - b2f(hb));
                    unsigned short hu, lu;
                    __builtin_memcpy(&hu, &hb, 2); __builtin_memcpy(&lu, &lb, 2);
                    int loff = row * ASTR + ((c * 2) ^ ((row & 7) << 4));
                    *(unsigned short*)(AhiN + loff) = hu;
                    *(unsigned short*)(AloN + loff) = lu;
                    st4_sc(slot + (size_t)row * HSZ + c, (unsigned)hu | ((unsigned)lu << 16));
                }
            }
            asm volatile("s_waitcnt vmcnt(0)" ::: "memory");
            __syncthreads();
            if (tid < 2) st4i(tid ? mycons : myprod, t + 1);
        }

    } else if (bid < 48) {
        // ===== stage L1a: z[t] = h0[t]@Wih1 + bih1 + bhh1 =====
        const int r = bid - 32;
        const bf16* Whi = ws + O_WIH1HI; const bf16* Wlo = ws + O_WIH1LO;
        char* Ahi = smem; char* Alo = smem + APLANE;
        int* myprod = PRODP(32 + r);
        int* mycons = CONSP(32 + r);
        const int* pprod = PRODP(16 + r);       // L0
        const int* ccons = CONSP(48 + r);       // L1b consumed
        const unsigned* h0ring = (const unsigned*)((char*)ws + O_H0RING) + (size_t)r * GRPW;
        float* zring = (float*)((char*)ws + O_ZRING) + (size_t)r * GRPW;
        const int colbase = wv * 64;
        float bias[4];
#pragma unroll
        for (int ni = 0; ni < 4; ni++) { int c = colbase + ni*16 + l15; bias[ni] = bih1[c] + bhh1[c]; }

        for (int t = 0; t < TLEN; ++t) {
            // ONE poll: h0[t] ready AND L1b released z slot (t-2)
            poll2(pprod, t + 1, ccons, t - 1, lane, wv);
            u32x4 pf[4];
            pref4sc(h0ring + (size_t)(t & 1) * SLOTW, tid, pf);
            awrite4(Ahi, Alo, tid, pf, 0);
            __syncthreads();
            if (tid == 0) st4i(mycons, t + 1);            // early release of h0 slot
            f32x4 accA[4] = {}, accB[4] = {};
            kloop512(Ahi, Alo, Whi, Wlo, l15, quad, colbase, accA, accB);
            f32x4 zv[4];
#pragma unroll
            for (int ni = 0; ni < 4; ni++)
#pragma unroll
                for (int rr = 0; rr < 4; rr++) zv[ni][rr] = accA[ni][rr] + accB[ni][rr] + bias[ni];
            st16sc(zring + (size_t)(t & 1) * SLOTW + tid * 16, zv);
            asm volatile("s_waitcnt vmcnt(0)" ::: "memory");
            __syncthreads();
            if (tid == 0) st4i(myprod, t + 1);
        }

    } else if (bid < 64) {
        // ===== stage L1b: h1[t] = tanh(z[t] + h1[t-1]@Whh1); state in LDS dbuf =====
        const int r = bid - 48;
        const bf16* Whi = ws + O_WHH1HI; const bf16* Wlo = ws + O_WHH1LO;
        char* A0 = smem;
        int* myprod = PRODP(48 + r);
        int* mycons = CONSP(48 + r);
        const int* pprod = PRODP(32 + r);       // L1a
        const int* ccons = CONSP(64 + (r >> 1)); // FC consumed
        const float* zring = (const float*)((char*)ws + O_ZRING) + (size_t)r * GRPW;
        unsigned* h1ring = (unsigned*)((char*)ws + O_H1RING) + (size_t)r * GRPW;
        const int colbase = wv * 64;

        for (int i = tid * 4; i < 2 * APLANE; i += 512 * 4) *(unsigned*)(A0 + i) = 0u;
        __syncthreads();

        for (int t = 0; t < TLEN; ++t) {
            const int cur = t & 1;
            const char* Ahi = A0 + (cur*2 + 0) * APLANE;
            const char* Alo = A0 + (cur*2 + 1) * APLANE;
            char* AhiN = A0 + ((cur^1)*2 + 0) * APLANE;
            char* AloN = A0 + ((cur^1)*2 + 1) * APLANE;
            f32x4 accA[4] = {}, accB[4] = {};
            kloop512(Ahi, Alo, Whi, Wlo, l15, quad, colbase, accA, accB);
            // ONE poll: z[t] ready AND FC released h1 slot (t-2)
            poll2(pprod, t + 1, ccons, t - 1, lane, wv);
            f32x4 zc[4];
            ld64sc(zring + (size_t)(t & 1) * SLOTW + tid * 16, zc);
            unsigned* slot = h1ring + (size_t)(t & 1) * SLOTW;
#pragma unroll
            for (int ni = 0; ni < 4; ni++) {
                int c = colbase + ni*16 + l15;
#pragma unroll
                for (int rr = 0; rr < 4; rr++) {
                    int row = quad*4 + rr;
                    float v = tanhf(accA[ni][rr] + accB[ni][rr] + zc[ni][rr]);
                    bf16 hb = __float2bfloat16(v);
                    bf16 lb = __float2bfloat16(v - b2f(hb));
                    unsigned short hu, lu;
                    __builtin_memcpy(&hu, &hb, 2); __builtin_memcpy(&lu, &lb, 2);
                    int loff = row * ASTR + ((c * 2) ^ ((row & 7) << 4));
                    *(unsigned short*)(AhiN + loff) = hu;
                    *(unsigned short*)(AloN + loff) = lu;
                    st4_sc(slot + (size_t)row * HSZ + c, (unsigned)hu | ((unsigned)lu << 16));
                }
            }
            asm volatile("s_waitcnt vmcnt(0)" ::: "memory");
            __syncthreads();
            if (tid < 2) st4i(tid ? mycons : myprod, t + 1);
        }

    } else {
        // ===== stage FC: logits[:,t,:] = h1[t] @ Wfc + bfc (32 rows/block) =====
        const int f = bid - 64, mb = f * 32;
        const bf16* Whi = ws + O_WFCHI; const bf16* Wlo = ws + O_WFCLO;
        char* Ahi = smem;
        char* Alo = smem + 32768;
        int* mycons = CONSP(64 + f);
        const int* p1 = PRODP(48 + 2*f);
        const int* p2 = PRODP(48 + 2*f + 1);
        const unsigned* ring1 = (const unsigned*)((char*)ws + O_H1RING) + (size_t)(2*f) * GRPW;
        const unsigned* ring2 = (const unsigned*)((char*)ws + O_H1RING) + (size_t)(2*f + 1) * GRPW;
        const int col = wv * 16 + l15;
        const float bias = bfc[col];
        const bf16* wh = Whi + (size_t)col * HSZ + quad*8;
        const bf16* wl = Wlo + (size_t)col * HSZ + quad*8;
        const int swz = (l15 & 7) << 4;

        for (int t = 0; t < TLEN; ++t) {
            poll2(p1, t + 1, p2, t + 1, lane, wv);         // one RT for both producers
            u32x4 pf[8];
            pref8sc(ring1 + (size_t)(t & 1) * SLOTW, ring2 + (size_t)(t & 1) * SLOTW, tid, pf);
            awrite4(Ahi, Alo, tid, pf, 0);
            awrite4(Ahi, Alo, tid, pf + 4, 16);
            __syncthreads();
            if (tid == 0) st4i(mycons, t + 1);             // release h1 slots early
            f32x4 accA[2] = {}, accB[2] = {};
            short8 bh2[2], bl2[2];
            bh2[0] = ld8(wh); bl2[0] = ld8(wl);
#pragma unroll
            for (int kc = 0; kc < 16; kc++) {
                const int cb = kc & 1, nb2 = cb ^ 1;
                if (kc < 15) { bh2[nb2] = ld8(wh + (kc+1)*32); bl2[nb2] = ld8(wl + (kc+1)*32); }
#pragma unroll
                for (int mi = 0; mi < 2; mi++) {
                    int aoff = (mi*16 + l15) * ASTR + ((kc*64 + quad*16) ^ swz);
                    short8 ah = *(const short8*)(Ahi + aoff);
                    short8 al = *(const short8*)(Alo + aoff);
                    accA[mi] = MFMA(ah, bh2[cb], accA[mi]);
                    accB[mi] = MFMA(al, bh2[cb], accB[mi]);
                    accB[mi] = MFMA(ah, bl2[cb], accB[mi]);
                }
            }
#pragma unroll
            for (int mi = 0; mi < 2; mi++)
#pragma unroll
                for (int rr = 0; rr < 4; rr++) {
                    int row = mb + mi*16 + quad*4 + rr;
                    out[((size_t)row * TLEN + t) * VSZ + col] = accA[mi][rr] + accB[mi][rr] + bias;
                }
        }
    }
#undef PRODP
#undef CONSP
}

extern "C" void kernel_launch(void* const* d_in, const int* in_sizes, int n_in,
                              void* d_out, int out_size, void* d_ws, size_t ws_size,
                              hipStream_t stream) {
    const int*   x    = (const int*)d_in[0];
    const float* emb  = (const float*)d_in[1];
    const float* Wih0 = (const float*)d_in[2];
    const float* bih0 = (const float*)d_in[3];
    const float* Whh0 = (const float*)d_in[4];
    const float* bhh0 = (const float*)d_in[5];
    const float* Wih1 = (const float*)d_in[6];
    const float* bih1 = (const float*)d_in[7];
    const float* Whh1 = (const float*)d_in[8];
    const float* bhh1 = (const float*)d_in[9];
    const float* Wfc  = (const float*)d_in[10];
    const float* bfc  = (const float*)d_in[11];
    float* out = (float*)d_out;
    bf16* ws   = (bf16*)d_ws;

    const int total = 3 * HSZ * HSZ + HSZ * EMBD + VSZ * HSZ + VSZ * EMBD
                    + NBLK * CTR_STRIDE * 2;
    k_prep<<<(total + 255) / 256, 256, 0, stream>>>(emb, Wih0, Whh0, Wih1, Whh1, Wfc, ws);

    k_persist<<<NBLK, 512, SMEMSZ, stream>>>(x, bih0, bhh0, bih1, bhh1, bfc, ws, out);
}

// Round 6
// 9038.651 us; speedup vs baseline: 1.8631x; 1.8631x over previous
//
#include <hip/hip_runtime.h>
#include <hip/hip_bf16.h>

#define VSZ 128
#define EMBD 64
#define HSZ 512
#define BSZ 256
#define TLEN 512
#define NBLK 136             // 64 X + 64 Y + 8 FC

typedef __attribute__((ext_vector_type(8))) short short8;
typedef __attribute__((ext_vector_type(4))) float f32x4;
typedef __attribute__((ext_vector_type(4))) unsigned int u32x4;
typedef __hip_bfloat16 bf16;

#define SQ   ((size_t)HSZ*HSZ)

// ---- weight region (bf16 element offsets; layout identical to prior rounds) ----
#define O_WHH0HI ((size_t)0)
#define O_WHH0LO (O_WHH0HI + SQ)
#define O_WIH1HI (O_WHH0LO + SQ)
#define O_WIH1LO (O_WIH1HI + SQ)
#define O_WHH1HI (O_WIH1LO + SQ)
#define O_WHH1LO (O_WHH1HI + SQ)
#define O_WIH0HI (O_WHH1LO + SQ)                 // [N=512][K=64]
#define O_WIH0LO (O_WIH0HI + (size_t)HSZ*EMBD)
#define O_WFCHI  (O_WIH0LO + (size_t)HSZ*EMBD)   // [N=128][K=512]
#define O_WFCLO  (O_WFCHI + (size_t)VSZ*HSZ)
#define O_EMBHI  (O_WFCLO + (size_t)VSZ*HSZ)     // [128][64]
#define O_EMBLO  (O_EMBHI + (size_t)VSZ*EMBD)
// weights end at byte 3,571,712

// ---- rings: depth-3, u32-packed hi|lo, [16 rg][3 slot][4 q][16 row][128 col] ----
#define O_RINGB  ((size_t)3571712)
#define RGRING   (3*8192)                         // u32 per rowgroup (3 slots x 8192)
#define O_H0R_B  (O_RINGB)
#define O_H1R_B  (O_RINGB + (size_t)16*RGRING*4)
#define O_CTR_B  (O_H1R_B + (size_t)16*RGRING*4)  // 224 counters x 256B
#define CTRN     224

#define ASTR   1024           // A-plane row stride bytes (swizzled)
#define SMEMSZ 65536

static __device__ __forceinline__ short8 ld8(const bf16* p) { return *(const short8*)p; }
static __device__ __forceinline__ float b2f(bf16 v) { return __bfloat162float(v); }
#define MFMA(a,b,c) __builtin_amdgcn_mfma_f32_16x16x32_bf16((a),(b),(c),0,0,0)

// ---- device-scope primitives (all loads wait inside their asm block) ----
static __device__ __forceinline__ void st4_sc(void* p, unsigned v) {
    asm volatile("global_store_dword %0, %1, off sc0 sc1" :: "v"(p), "v"(v) : "memory");
}
static __device__ __forceinline__ void st4i(int* p, int v) { st4_sc(p, (unsigned)v); }
static __device__ __forceinline__ void pref4sc(const unsigned* base, int tid, u32x4* v) {
    const unsigned* p0 = base + 0*2048 + tid*4;
    const unsigned* p1 = base + 1*2048 + tid*4;
    const unsigned* p2 = base + 2*2048 + tid*4;
    const unsigned* p3 = base + 3*2048 + tid*4;
    asm volatile(
        "global_load_dwordx4 %0, %4, off sc0 sc1\n\t"
        "global_load_dwordx4 %1, %5, off sc0 sc1\n\t"
        "global_load_dwordx4 %2, %6, off sc0 sc1\n\t"
        "global_load_dwordx4 %3, %7, off sc0 sc1\n\t"
        "s_waitcnt vmcnt(0)"
        : "=&v"(v[0]), "=&v"(v[1]), "=&v"(v[2]), "=&v"(v[3])
        : "v"(p0), "v"(p1), "v"(p2), "v"(p3) : "memory");
}
static __device__ __forceinline__ void pref8sc(const unsigned* b1, const unsigned* b2,
                                               int tid, u32x4* v) {
    const unsigned* q0 = b1 + 0*2048 + tid*4; const unsigned* q1 = b1 + 1*2048 + tid*4;
    const unsigned* q2 = b1 + 2*2048 + tid*4; const unsigned* q3 = b1 + 3*2048 + tid*4;
    const unsigned* q4 = b2 + 0*2048 + tid*4; const unsigned* q5 = b2 + 1*2048 + tid*4;
    const unsigned* q6 = b2 + 2*2048 + tid*4; const unsigned* q7 = b2 + 3*2048 + tid*4;
    asm volatile(
        "global_load_dwordx4 %0, %8, off sc0 sc1\n\t"
        "global_load_dwordx4 %1, %9, off sc0 sc1\n\t"
        "global_load_dwordx4 %2, %10, off sc0 sc1\n\t"
        "global_load_dwordx4 %3, %11, off sc0 sc1\n\t"
        "global_load_dwordx4 %4, %12, off sc0 sc1\n\t"
        "global_load_dwordx4 %5, %13, off sc0 sc1\n\t"
        "global_load_dwordx4 %6, %14, off sc0 sc1\n\t"
        "global_load_dwordx4 %7, %15, off sc0 sc1\n\t"
        "s_waitcnt vmcnt(0)"
        : "=&v"(v[0]), "=&v"(v[1]), "=&v"(v[2]), "=&v"(v[3]),
          "=&v"(v[4]), "=&v"(v[5]), "=&v"(v[6]), "=&v"(v[7])
        : "v"(q0), "v"(q1), "v"(q2), "v"(q3), "v"(q4), "v"(q5), "v"(q6), "v"(q7)
        : "memory");
}
static __device__ __forceinline__ void ld3x16sc(const unsigned* p0, const unsigned* p1,
                                                const unsigned* p2, u32x4* v) {
    asm volatile(
        "global_load_dwordx4 %0, %3, off sc0 sc1\n\t"
        "global_load_dwordx4 %1, %4, off sc0 sc1\n\t"
        "global_load_dwordx4 %2, %5, off sc0 sc1\n\t"
        "s_waitcnt vmcnt(0)"
        : "=&v"(v[0]), "=&v"(v[1]), "=&v"(v[2])
        : "v"(p0), "v"(p1), "v"(p2) : "memory");
}
// per-lane poll: each active wave-0 lane spins on its own (ptr, need); exits together
static __device__ __forceinline__ void pollv(const int* p, int need, bool act, int wv) {
    if (wv == 0) {
        for (int it = 0; it < (1 << 17); ++it) {
            int ok = 1;
            if (act) {
                int v;
                asm volatile("global_load_dword %0, %1, off sc0 sc1\n\t"
                             "s_waitcnt vmcnt(0)" : "=v"(v) : "v"(p) : "memory");
                ok = (v >= need);
            }
            if (__all(ok)) break;
            __builtin_amdgcn_s_sleep(2);
        }
    }
    __syncthreads();
}
// unpack one u32x4 (4 packed cols of one row) into swizzled hi/lo A-planes
static __device__ __forceinline__ void awriteQ(char* Ahi, char* Alo, int tid,
                                               u32x4 v, int rowoff, int kbase) {
    int row = rowoff + (tid >> 5);
    int colb = kbase * 2 + (tid & 31) * 8;
    int off = row * ASTR + (colb ^ ((row & 7) << 4));
    uint2 hi, lo;
    hi.x = (v[0] & 0xffffu) | (v[1] << 16);  hi.y = (v[2] & 0xffffu) | (v[3] << 16);
    lo.x = (v[0] >> 16) | (v[1] & 0xffff0000u); lo.y = (v[2] >> 16) | (v[3] & 0xffff0000u);
    *(uint2*)(Ahi + off) = hi;
    *(uint2*)(Alo + off) = lo;
}

// ---- prep: split/transpose weights + zero counters ----
__global__ void k_prep(const float* __restrict__ emb, const float* __restrict__ Wih0,
                       const float* __restrict__ Whh0, const float* __restrict__ Wih1,
                       const float* __restrict__ Whh1, const float* __restrict__ Wfc,
                       bf16* __restrict__ ws) {
    int j = blockIdx.x * blockDim.x + threadIdx.x;
    const int SQi = HSZ * HSZ;
    if (j < SQi) {
        int n = j / HSZ, k = j - n * HSZ;
        float w = Whh0[k * HSZ + n];
        bf16 hi = __float2bfloat16(w);
        ws[O_WHH0HI + j] = hi; ws[O_WHH0LO + j] = __float2bfloat16(w - b2f(hi));
        return;
    }
    j -= SQi;
    if (j < SQi) {
        int n = j / HSZ, k = j - n * HSZ;
        float w = Wih1[k * HSZ + n];
        bf16 hi = __float2bfloat16(w);
        ws[O_WIH1HI + j] = hi; ws[O_WIH1LO + j] = __float2bfloat16(w - b2f(hi));
        return;
    }
    j -= SQi;
    if (j < SQi) {
        int n = j / HSZ, k = j - n * HSZ;
        float w = Whh1[k * HSZ + n];
        bf16 hi = __float2bfloat16(w);
        ws[O_WHH1HI + j] = hi; ws[O_WHH1LO + j] = __float2bfloat16(w - b2f(hi));
        return;
    }
    j -= SQi;
    if (j < HSZ * EMBD) {
        int n = j / EMBD, k = j - n * EMBD;
        float w = Wih0[k * HSZ + n];
        bf16 hi = __float2bfloat16(w);
        ws[O_WIH0HI + j] = hi; ws[O_WIH0LO + j] = __float2bfloat16(w - b2f(hi));
        return;
    }
    j -= HSZ * EMBD;
    if (j < VSZ * HSZ) {
        int n = j / HSZ, k = j - n * HSZ;
        float w = Wfc[k * VSZ + n];
        bf16 hi = __float2bfloat16(w);
        ws[O_WFCHI + j] = hi; ws[O_WFCLO + j] = __float2bfloat16(w - b2f(hi));
        return;
    }
    j -= VSZ * HSZ;
    if (j < VSZ * EMBD) {
        float w = emb[j];
        bf16 hi = __float2bfloat16(w);
        ws[O_EMBHI + j] = hi; ws[O_EMBLO + j] = __float2bfloat16(w - b2f(hi));
        return;
    }
    j -= VSZ * EMBD;
    if (j < CTRN * 64) ((int*)((char*)ws + O_CTR_B))[j] = 0;
}

// ---- persistent 2-serial-stage pipeline: X(h0) -> Y(h1 split-phase) -> FC(off-path) ----
__global__ __launch_bounds__(512, 1) void k_persist(
    const int* __restrict__ x,
    const float* __restrict__ bih0, const float* __restrict__ bhh0,
    const float* __restrict__ bih1, const float* __restrict__ bhh1,
    const float* __restrict__ bfc,
    bf16* __restrict__ ws, float* __restrict__ out)
{
    extern __shared__ char smem[];
    const int tid = (int)threadIdx.x;
    const int lane = tid & 63;
    const int wv   = tid >> 6;
    const int l15  = lane & 15;
    const int quad = lane >> 4;
    const int bid  = (int)blockIdx.x;
    const int swz  = (l15 & 7) << 4;

    int* CTR = (int*)((char*)ws + O_CTR_B);
#define XPROD(rg,qq) (CTR + (size_t)((rg)*4+(qq))*64)
#define YPROD(rg,qq) (CTR + (size_t)(64+(rg)*4+(qq))*64)
#define YCONS(rg,qq) (CTR + (size_t)(136+(rg)*4+(qq))*64)
#define FCC(f)       (CTR + (size_t)(200+(f))*64)
#define H0R(rg) ((unsigned*)((char*)ws + O_H0R_B) + (size_t)(rg)*RGRING)
#define H1R(rg) ((unsigned*)((char*)ws + O_H1R_B) + (size_t)(rg)*RGRING)

    if (bid < 64) {
        // ======== X(rg,q): h0[t][16 rows, 128 cols] = tanh(emb@Wih0 + h0[t-1]@Whh0 + b) ========
        const int rg = bid >> 2, q = bid & 3, mb = rg * 16, qb = q * 128;
        char* Ahi = smem;           // h0[t-1] full-row A planes (16KB each)
        char* Alo = smem + 16384;
        char* Ehi = smem + 32768;   // emb A planes (2KB each)
        char* Elo = smem + 34816;
        const bf16* embhi = ws + O_EMBHI; const bf16* emblo = ws + O_EMBLO;
        const int col = qb + wv * 16 + l15;
        const float bias = bih0[col] + bhh0[col];
        const bf16* wch = ws + O_WHH0HI + (size_t)col * HSZ + quad * 8;
        const bf16* wcl = ws + O_WHH0LO + (size_t)col * HSZ + quad * 8;
        const bf16* ech = ws + O_WIH0HI + (size_t)col * EMBD + quad * 8;
        const bf16* ecl = ws + O_WIH0LO + (size_t)col * EMBD + quad * 8;
        unsigned* h0r = H0R(rg);
        const int qa = (q + 1) & 3, qb2 = (q + 2) & 3, qc = (q + 3) & 3;

        for (int i = tid * 4; i < 32768; i += 2048) *(unsigned*)(smem + i) = 0u; // h0[-1]=0
        __syncthreads();

        int scur = 0;
        for (int t = 0; t < TLEN; ++t) {
            const int sp = (scur == 0) ? 2 : scur - 1;
            // poll: 3 sibling X prods >= t; 4 Y released h0[t-3]
            const int* pp = nullptr; int nd = 0; bool act = false;
            if (wv == 0) {
                if (lane < 3) {
                    int ss = (lane == 0) ? qa : (lane == 1) ? qb2 : qc;
                    pp = XPROD(rg, ss); nd = t; act = (t > 0);
                } else if (lane < 7) {
                    pp = YCONS(rg, lane - 3); nd = t - 2; act = (t >= 3);
                }
            }
            pollv(pp, nd, act, wv);
            // stage: 3 sibling h0[t-1] quarters -> A planes; emb rows -> E planes
            if (t > 0) {
                const unsigned* sl = h0r + (size_t)sp * 8192;
                u32x4 v3[3];
                ld3x16sc(sl + qa*2048 + tid*4, sl + qb2*2048 + tid*4, sl + qc*2048 + tid*4, v3);
                awriteQ(Ahi, Alo, tid, v3[0], 0, qa * 128);
                awriteQ(Ahi, Alo, tid, v3[1], 0, qb2 * 128);
                awriteQ(Ahi, Alo, tid, v3[2], 0, qc * 128);
            }
            if (tid < 128) {
                int row = tid >> 3, oct = tid & 7;
                int xr = x[(size_t)(mb + row) * TLEN + t];
                int eoff = row * 128 + ((oct * 16) ^ ((row & 7) << 4));
                *(short8*)(Ehi + eoff) = ld8(embhi + (size_t)xr * EMBD + oct * 8);
                *(short8*)(Elo + eoff) = ld8(emblo + (size_t)xr * EMBD + oct * 8);
            }
            __syncthreads();
            // kloop: emb part (K=64) + recurrent part (K=512)
            f32x4 accA = {}, accB = {};
#pragma unroll
            for (int kc = 0; kc < 2; kc++) {
                int aoff = l15 * 128 + ((kc * 64 + quad * 16) ^ swz);
                short8 ah = *(const short8*)(Ehi + aoff);
                short8 al = *(const short8*)(Elo + aoff);
                short8 bh = ld8(ech + kc * 32);
                short8 bl = ld8(ecl + kc * 32);
                accA = MFMA(ah, bh, accA); accB = MFMA(al, bh, accB); accB = MFMA(ah, bl, accB);
            }
#pragma unroll
            for (int kc = 0; kc < 16; kc++) {
                int aoff = l15 * ASTR + ((kc * 64 + quad * 16) ^ swz);
                short8 ah = *(const short8*)(Ahi + aoff);
                short8 al = *(const short8*)(Alo + aoff);
                short8 bh = ld8(wch + kc * 32);
                short8 bl = ld8(wcl + kc * 32);
                accA = MFMA(ah, bh, accA); accB = MFMA(al, bh, accB); accB = MFMA(ah, bl, accB);
            }
            __syncthreads();                 // all A reads done before own-quarter overwrite
            // epilogue: tanh -> own LDS quarter + ring quarter
            unsigned* slot = h0r + (size_t)scur * 8192 + q * 2048;
#pragma unroll
            for (int rr = 0; rr < 4; rr++) {
                int row = quad * 4 + rr;
                float v = tanhf(accA[rr] + accB[rr] + bias);
                bf16 hb = __float2bfloat16(v);
                bf16 lb = __float2bfloat16(v - b2f(hb));
                unsigned short hu, lu;
                __builtin_memcpy(&hu, &hb, 2); __builtin_memcpy(&lu, &lb, 2);
                int loff = row * ASTR + ((col * 2) ^ ((row & 7) << 4));
                *(unsigned short*)(Ahi + loff) = hu;
                *(unsigned short*)(Alo + loff) = lu;
                st4_sc(slot + (size_t)row * 128 + wv * 16 + l15,
                       (unsigned)hu | ((unsigned)lu << 16));
            }
            asm volatile("s_waitcnt vmcnt(0)" ::: "memory");
            __syncthreads();
            if (tid == 0) st4i(XPROD(rg, q), t + 1);
            scur = (scur == 2) ? 0 : scur + 1;
        }

    } else if (bid < 128) {
        // ======== Y(rg,q): h1[t][16,128] = tanh(h1[t-1]@Whh1 [p1] + h0[t]@Wih1 [p2] + b) ========
        const int rg = (bid - 64) >> 2, q = (bid - 64) & 3, qb = q * 128;
        char* A1hi = smem;            // h1[t-1] planes
        char* A1lo = smem + 16384;
        char* A2hi = smem + 32768;    // h0[t] planes
        char* A2lo = smem + 49152;
        const int col = qb + wv * 16 + l15;
        const float bias = bih1[col] + bhh1[col];
        const bf16* whh = ws + O_WHH1HI + (size_t)col * HSZ + quad * 8;
        const bf16* whl = ws + O_WHH1LO + (size_t)col * HSZ + quad * 8;
        const bf16* w1h = ws + O_WIH1HI + (size_t)col * HSZ + quad * 8;
        const bf16* w1l = ws + O_WIH1LO + (size_t)col * HSZ + quad * 8;
        unsigned* h1r = H1R(rg);
        const unsigned* h0r = H0R(rg);
        const int qa = (q + 1) & 3, qb2 = (q + 2) & 3, qc = (q + 3) & 3;
        const int f = rg >> 1;

        for (int i = tid * 4; i < 32768; i += 2048) *(unsigned*)(smem + i) = 0u; // h1[-1]=0
        __syncthreads();

        int scur = 0;
        for (int t = 0; t < TLEN; ++t) {
            const int sp = (scur == 0) ? 2 : scur - 1;
            // p1 poll: 3 sibling Y prods >= t; FC released h1[t-3]
            const int* pp = nullptr; int nd = 0; bool act = false;
            if (wv == 0) {
                if (lane < 3) {
                    int ss = (lane == 0) ? qa : (lane == 1) ? qb2 : qc;
                    pp = YPROD(rg, ss); nd = t; act = (t > 0);
                } else if (lane == 3) { pp = FCC(f); nd = t - 2; act = (t >= 3); }
            }
            pollv(pp, nd, act, wv);
            if (t > 0) {
                const unsigned* sl = h1r + (size_t)sp * 8192;
                u32x4 v3[3];
                ld3x16sc(sl + qa*2048 + tid*4, sl + qb2*2048 + tid*4, sl + qc*2048 + tid*4, v3);
                awriteQ(A1hi, A1lo, tid, v3[0], 0, qa * 128);
                awriteQ(A1hi, A1lo, tid, v3[1], 0, qb2 * 128);
                awriteQ(A1hi, A1lo, tid, v3[2], 0, qc * 128);
            }
            __syncthreads();
            // p1 kloop: h1[t-1] @ Whh1
            f32x4 accA = {}, accB = {};
#pragma unroll
            for (int kc = 0; kc < 16; kc++) {
                int aoff = l15 * ASTR + ((kc * 64 + quad * 16) ^ swz);
                short8 ah = *(const short8*)(A1hi + aoff);
                short8 al = *(const short8*)(A1lo + aoff);
                short8 bh = ld8(whh + kc * 32);
                short8 bl = ld8(whl + kc * 32);
                accA = MFMA(ah, bh, accA); accB = MFMA(al, bh, accB); accB = MFMA(ah, bl, accB);
            }
            // p2 poll: 4 X prods >= t+1 (h0[t] ready)
            pp = nullptr; nd = 0; act = false;
            if (wv == 0 && lane < 4) { pp = XPROD(rg, lane); nd = t + 1; act = true; }
            pollv(pp, nd, act, wv);
            u32x4 pf[4];
            pref4sc(h0r + (size_t)scur * 8192, tid, pf);
#pragma unroll
            for (int c = 0; c < 4; c++) awriteQ(A2hi, A2lo, tid, pf[c], 0, c * 128);
            __syncthreads();
            if (tid == 0) st4i(YCONS(rg, q), t + 1);       // release h0[t] slot
            // p2 kloop: h0[t] @ Wih1 (same accumulators)
#pragma unroll
            for (int kc = 0; kc < 16; kc++) {
                int aoff = l15 * ASTR + ((kc * 64 + quad * 16) ^ swz);
                short8 ah = *(const short8*)(A2hi + aoff);
                short8 al = *(const short8*)(A2lo + aoff);
                short8 bh = ld8(w1h + kc * 32);
                short8 bl = ld8(w1l + kc * 32);
                accA = MFMA(ah, bh, accA); accB = MFMA(al, bh, accB); accB = MFMA(ah, bl, accB);
            }
            __syncthreads();                 // A1 reads (p1) long done; order before overwrite
            // epilogue
            unsigned* slot = h1r + (size_t)scur * 8192 + q * 2048;
#pragma unroll
            for (int rr = 0; rr < 4; rr++) {
                int row = quad * 4 + rr;
                float v = tanhf(accA[rr] + accB[rr] + bias);
                bf16 hb = __float2bfloat16(v);
                bf16 lb = __float2bfloat16(v - b2f(hb));
                unsigned short hu, lu;
                __builtin_memcpy(&hu, &hb, 2); __builtin_memcpy(&lu, &lb, 2);
                int loff = row * ASTR + ((col * 2) ^ ((row & 7) << 4));
                *(unsigned short*)(A1hi + loff) = hu;
                *(unsigned short*)(A1lo + loff) = lu;
                st4_sc(slot + (size_t)row * 128 + wv * 16 + l15,
                       (unsigned)hu | ((unsigned)lu << 16));
            }
            asm volatile("s_waitcnt vmcnt(0)" ::: "memory");
            __syncthreads();
            if (tid == 0) st4i(YPROD(rg, q), t + 1);
            scur = (scur == 2) ? 0 : scur + 1;
        }

    } else {
        // ======== FC(f): logits[32 rows, t, 128] = h1[t] @ Wfc + b (off critical path) ========
        const int f = bid - 128;
        char* FAhi = smem;            // 32-row planes
        char* FAlo = smem + 32768;
        const int col = wv * 16 + l15;
        const float bias = bfc[col];
        const bf16* wfh = ws + O_WFCHI + (size_t)col * HSZ + quad * 8;
        const bf16* wfl = ws + O_WFCLO + (size_t)col * HSZ + quad * 8;
        const unsigned* r1 = H1R(2 * f);
        const unsigned* r2 = H1R(2 * f + 1);

        int scur = 0;
        for (int t = 0; t < TLEN; ++t) {
            // poll: 8 Y producers (2 rgs x 4 quarters) >= t+1
            const int* pp = nullptr; int nd = 0; bool act = false;
            if (wv == 0 && lane < 8) {
                pp = YPROD(2 * f + (lane >> 2), lane & 3); nd = t + 1; act = true;
            }
            pollv(pp, nd, act, wv);
            u32x4 pf[8];
            pref8sc(r1 + (size_t)scur * 8192, r2 + (size_t)scur * 8192, tid, pf);
#pragma unroll
            for (int i = 0; i < 8; i++)
                awriteQ(FAhi, FAlo, tid, pf[i], (i >> 2) * 16, (i & 3) * 128);
            __syncthreads();
            if (tid == 0) st4i(FCC(f), t + 1);             // release h1[t] slots
            f32x4 accA[2] = {}, accB[2] = {};
#pragma unroll
            for (int kc = 0; kc < 16; kc++) {
                short8 bh = ld8(wfh + kc * 32);
                short8 bl = ld8(wfl + kc * 32);
#pragma unroll
                for (int mi = 0; mi < 2; mi++) {
                    int aoff = (mi * 16 + l15) * ASTR + ((kc * 64 + quad * 16) ^ swz);
                    short8 ah = *(const short8*)(FAhi + aoff);
                    short8 al = *(const short8*)(FAlo + aoff);
                    accA[mi] = MFMA(ah, bh, accA[mi]);
                    accB[mi] = MFMA(al, bh, accB[mi]);
                    accB[mi] = MFMA(ah, bl, accB[mi]);
                }
            }
#pragma unroll
            for (int mi = 0; mi < 2; mi++)
#pragma unroll
                for (int rr = 0; rr < 4; rr++) {
                    int row = 32 * f + mi * 16 + quad * 4 + rr;
                    out[((size_t)row * TLEN + t) * VSZ + col] = accA[mi][rr] + accB[mi][rr] + bias;
                }
            scur = (scur == 2) ? 0 : scur + 1;
        }
    }
#undef XPROD
#undef YPROD
#undef YCONS
#undef FCC
#undef H0R
#undef H1R
}

extern "C" void kernel_launch(void* const* d_in, const int* in_sizes, int n_in,
                              void* d_out, int out_size, void* d_ws, size_t ws_size,
                              hipStream_t stream) {
    const int*   x    = (const int*)d_in[0];
    const float* emb  = (const float*)d_in[1];
    const float* Wih0 = (const float*)d_in[2];
    const float* bih0 = (const float*)d_in[3];
    const float* Whh0 = (const float*)d_in[4];
    const float* bhh0 = (const float*)d_in[5];
    const float* Wih1 = (const float*)d_in[6];
    const float* bih1 = (const float*)d_in[7];
    const float* Whh1 = (const float*)d_in[8];
    const float* bhh1 = (const float*)d_in[9];
    const float* Wfc  = (const float*)d_in[10];
    const float* bfc  = (const float*)d_in[11];
    float* out = (float*)d_out;
    bf16* ws   = (bf16*)d_ws;

    const int total = 3 * HSZ * HSZ + HSZ * EMBD + VSZ * HSZ + VSZ * EMBD + CTRN * 64;
    k_prep<<<(total + 255) / 256, 256, 0, stream>>>(emb, Wih0, Whh0, Wih1, Whh1, Wfc, ws);

    k_persist<<<NBLK, 512, SMEMSZ, stream>>>(x, bih0, bhh0, bih1, bhh1, bfc, ws, out);
}

// Round 7
// 8791.443 us; speedup vs baseline: 1.9155x; 1.0281x over previous
//
#include <hip/hip_runtime.h>
#include <hip/hip_bf16.h>

#define VSZ 128
#define EMBD 64
#define HSZ 512
#define BSZ 256
#define TLEN 512
#define NBLK 136             // 64 X + 64 Y + 8 FC

typedef __attribute__((ext_vector_type(8))) short short8;
typedef __attribute__((ext_vector_type(4))) float f32x4;
typedef __attribute__((ext_vector_type(4))) unsigned int u32x4;
typedef __hip_bfloat16 bf16;

#define SQ   ((size_t)HSZ*HSZ)

// ---- weight region (bf16 element offsets; layout identical to prior rounds) ----
#define O_WHH0HI ((size_t)0)
#define O_WHH0LO (O_WHH0HI + SQ)
#define O_WIH1HI (O_WHH0LO + SQ)
#define O_WIH1LO (O_WIH1HI + SQ)
#define O_WHH1HI (O_WIH1LO + SQ)
#define O_WHH1LO (O_WHH1HI + SQ)
#define O_WIH0HI (O_WHH1LO + SQ)                 // [N=512][K=64]
#define O_WIH0LO (O_WIH0HI + (size_t)HSZ*EMBD)
#define O_WFCHI  (O_WIH0LO + (size_t)HSZ*EMBD)   // [N=128][K=512]
#define O_WFCLO  (O_WFCHI + (size_t)VSZ*HSZ)
#define O_EMBHI  (O_WFCLO + (size_t)VSZ*HSZ)     // [128][64]
#define O_EMBLO  (O_EMBHI + (size_t)VSZ*EMBD)
// weights end at byte 3,571,712

// ---- rings: depth-3, u32-packed hi|lo, [16 rg][3 slot][4 q][16 row][128 col] ----
#define O_RINGB  ((size_t)3571712)
#define RGRING   (3*8192)                         // u32 per rowgroup (3 slots x 8192)
#define O_H0R_B  (O_RINGB)
#define O_H1R_B  (O_RINGB + (size_t)16*RGRING*4)
#define O_CTR_B  (O_H1R_B + (size_t)16*RGRING*4)  // 224 counters x 256B
#define CTRN     224

#define ASTR   1024           // A-plane row stride bytes (swizzled)
#define SMEMSZ 65536

static __device__ __forceinline__ short8 ld8(const bf16* p) { return *(const short8*)p; }
static __device__ __forceinline__ float b2f(bf16 v) { return __bfloat162float(v); }
#define MFMA(a,b,c) __builtin_amdgcn_mfma_f32_16x16x32_bf16((a),(b),(c),0,0,0)

// ---- device-scope primitives (all loads wait inside their asm block) ----
static __device__ __forceinline__ void st4_sc(void* p, unsigned v) {
    asm volatile("global_store_dword %0, %1, off sc0 sc1" :: "v"(p), "v"(v) : "memory");
}
static __device__ __forceinline__ void st4i(int* p, int v) { st4_sc(p, (unsigned)v); }
static __device__ __forceinline__ void pref4sc(const unsigned* base, int tid, u32x4* v) {
    const unsigned* p0 = base + 0*2048 + tid*4;
    const unsigned* p1 = base + 1*2048 + tid*4;
    const unsigned* p2 = base + 2*2048 + tid*4;
    const unsigned* p3 = base + 3*2048 + tid*4;
    asm volatile(
        "global_load_dwordx4 %0, %4, off sc0 sc1\n\t"
        "global_load_dwordx4 %1, %5, off sc0 sc1\n\t"
        "global_load_dwordx4 %2, %6, off sc0 sc1\n\t"
        "global_load_dwordx4 %3, %7, off sc0 sc1\n\t"
        "s_waitcnt vmcnt(0)"
        : "=&v"(v[0]), "=&v"(v[1]), "=&v"(v[2]), "=&v"(v[3])
        : "v"(p0), "v"(p1), "v"(p2), "v"(p3) : "memory");
}
static __device__ __forceinline__ void pref8sc(const unsigned* b1, const unsigned* b2,
                                               int tid, u32x4* v) {
    const unsigned* q0 = b1 + 0*2048 + tid*4; const unsigned* q1 = b1 + 1*2048 + tid*4;
    const unsigned* q2 = b1 + 2*2048 + tid*4; const unsigned* q3 = b1 + 3*2048 + tid*4;
    const unsigned* q4 = b2 + 0*2048 + tid*4; const unsigned* q5 = b2 + 1*2048 + tid*4;
    const unsigned* q6 = b2 + 2*2048 + tid*4; const unsigned* q7 = b2 + 3*2048 + tid*4;
    asm volatile(
        "global_load_dwordx4 %0, %8, off sc0 sc1\n\t"
        "global_load_dwordx4 %1, %9, off sc0 sc1\n\t"
        "global_load_dwordx4 %2, %10, off sc0 sc1\n\t"
        "global_load_dwordx4 %3, %11, off sc0 sc1\n\t"
        "global_load_dwordx4 %4, %12, off sc0 sc1\n\t"
        "global_load_dwordx4 %5, %13, off sc0 sc1\n\t"
        "global_load_dwordx4 %6, %14, off sc0 sc1\n\t"
        "global_load_dwordx4 %7, %15, off sc0 sc1\n\t"
        "s_waitcnt vmcnt(0)"
        : "=&v"(v[0]), "=&v"(v[1]), "=&v"(v[2]), "=&v"(v[3]),
          "=&v"(v[4]), "=&v"(v[5]), "=&v"(v[6]), "=&v"(v[7])
        : "v"(q0), "v"(q1), "v"(q2), "v"(q3), "v"(q4), "v"(q5), "v"(q6), "v"(q7)
        : "memory");
}
static __device__ __forceinline__ void ld3x16sc(const unsigned* p0, const unsigned* p1,
                                                const unsigned* p2, u32x4* v) {
    asm volatile(
        "global_load_dwordx4 %0, %3, off sc0 sc1\n\t"
        "global_load_dwordx4 %1, %4, off sc0 sc1\n\t"
        "global_load_dwordx4 %2, %5, off sc0 sc1\n\t"
        "s_waitcnt vmcnt(0)"
        : "=&v"(v[0]), "=&v"(v[1]), "=&v"(v[2])
        : "v"(p0), "v"(p1), "v"(p2) : "memory");
}
// 7-load batch (Y): 3 h1-sibling quarters + 4 h0 quarters, ONE wait
static __device__ __forceinline__ void ld7x16sc(
    const unsigned* p0, const unsigned* p1, const unsigned* p2,
    const unsigned* p3, const unsigned* p4, const unsigned* p5, const unsigned* p6,
    u32x4* v) {
    asm volatile(
        "global_load_dwordx4 %0, %7, off sc0 sc1\n\t"
        "global_load_dwordx4 %1, %8, off sc0 sc1\n\t"
        "global_load_dwordx4 %2, %9, off sc0 sc1\n\t"
        "global_load_dwordx4 %3, %10, off sc0 sc1\n\t"
        "global_load_dwordx4 %4, %11, off sc0 sc1\n\t"
        "global_load_dwordx4 %5, %12, off sc0 sc1\n\t"
        "global_load_dwordx4 %6, %13, off sc0 sc1\n\t"
        "s_waitcnt vmcnt(0)"
        : "=&v"(v[0]), "=&v"(v[1]), "=&v"(v[2]), "=&v"(v[3]),
          "=&v"(v[4]), "=&v"(v[5]), "=&v"(v[6])
        : "v"(p0), "v"(p1), "v"(p2), "v"(p3), "v"(p4), "v"(p5), "v"(p6)
        : "memory");
}
// per-lane poll: each active wave-0 lane spins on its own (ptr, need); exits together
static __device__ __forceinline__ void pollv(const int* p, int need, bool act, int wv) {
    if (wv == 0) {
        for (int it = 0; it < (1 << 17); ++it) {
            int ok = 1;
            if (act) {
                int v;
                asm volatile("global_load_dword %0, %1, off sc0 sc1\n\t"
                             "s_waitcnt vmcnt(0)" : "=v"(v) : "v"(p) : "memory");
                ok = (v >= need);
            }
            if (__all(ok)) break;
            __builtin_amdgcn_s_sleep(1);
        }
    }
    __syncthreads();
}
// unpack one u32x4 (4 packed cols of one row) into swizzled hi/lo A-planes
static __device__ __forceinline__ void awriteQ(char* Ahi, char* Alo, int tid,
                                               u32x4 v, int rowoff, int kbase) {
    int row = rowoff + (tid >> 5);
    int colb = kbase * 2 + (tid & 31) * 8;
    int off = row * ASTR + (colb ^ ((row & 7) << 4));
    uint2 hi, lo;
    hi.x = (v[0] & 0xffffu) | (v[1] << 16);  hi.y = (v[2] & 0xffffu) | (v[3] << 16);
    lo.x = (v[0] >> 16) | (v[1] & 0xffff0000u); lo.y = (v[2] >> 16) | (v[3] & 0xffff0000u);
    *(uint2*)(Ahi + off) = hi;
    *(uint2*)(Alo + off) = lo;
}

// ---- prep: split/transpose weights + zero counters ----
__global__ void k_prep(const float* __restrict__ emb, const float* __restrict__ Wih0,
                       const float* __restrict__ Whh0, const float* __restrict__ Wih1,
                       const float* __restrict__ Whh1, const float* __restrict__ Wfc,
                       bf16* __restrict__ ws) {
    int j = blockIdx.x * blockDim.x + threadIdx.x;
    const int SQi = HSZ * HSZ;
    if (j < SQi) {
        int n = j / HSZ, k = j - n * HSZ;
        float w = Whh0[k * HSZ + n];
        bf16 hi = __float2bfloat16(w);
        ws[O_WHH0HI + j] = hi; ws[O_WHH0LO + j] = __float2bfloat16(w - b2f(hi));
        return;
    }
    j -= SQi;
    if (j < SQi) {
        int n = j / HSZ, k = j - n * HSZ;
        float w = Wih1[k * HSZ + n];
        bf16 hi = __float2bfloat16(w);
        ws[O_WIH1HI + j] = hi; ws[O_WIH1LO + j] = __float2bfloat16(w - b2f(hi));
        return;
    }
    j -= SQi;
    if (j < SQi) {
        int n = j / HSZ, k = j - n * HSZ;
        float w = Whh1[k * HSZ + n];
        bf16 hi = __float2bfloat16(w);
        ws[O_WHH1HI + j] = hi; ws[O_WHH1LO + j] = __float2bfloat16(w - b2f(hi));
        return;
    }
    j -= SQi;
    if (j < HSZ * EMBD) {
        int n = j / EMBD, k = j - n * EMBD;
        float w = Wih0[k * HSZ + n];
        bf16 hi = __float2bfloat16(w);
        ws[O_WIH0HI + j] = hi; ws[O_WIH0LO + j] = __float2bfloat16(w - b2f(hi));
        return;
    }
    j -= HSZ * EMBD;
    if (j < VSZ * HSZ) {
        int n = j / HSZ, k = j - n * HSZ;
        float w = Wfc[k * VSZ + n];
        bf16 hi = __float2bfloat16(w);
        ws[O_WFCHI + j] = hi; ws[O_WFCLO + j] = __float2bfloat16(w - b2f(hi));
        return;
    }
    j -= VSZ * HSZ;
    if (j < VSZ * EMBD) {
        float w = emb[j];
        bf16 hi = __float2bfloat16(w);
        ws[O_EMBHI + j] = hi; ws[O_EMBLO + j] = __float2bfloat16(w - b2f(hi));
        return;
    }
    j -= VSZ * EMBD;
    if (j < CTRN * 64) ((int*)((char*)ws + O_CTR_B))[j] = 0;
}

// ---- persistent 2-serial-stage pipeline: X(h0) -> Y(h1, merged-edge) -> FC(off-path) ----
__global__ __launch_bounds__(512, 1) void k_persist(
    const int* __restrict__ x,
    const float* __restrict__ bih0, const float* __restrict__ bhh0,
    const float* __restrict__ bih1, const float* __restrict__ bhh1,
    const float* __restrict__ bfc,
    bf16* __restrict__ ws, float* __restrict__ out)
{
    extern __shared__ char smem[];
    const int tid = (int)threadIdx.x;
    const int lane = tid & 63;
    const int wv   = tid >> 6;
    const int l15  = lane & 15;
    const int quad = lane >> 4;
    const int bid  = (int)blockIdx.x;
    const int swz  = (l15 & 7) << 4;

    int* CTR = (int*)((char*)ws + O_CTR_B);
#define XPROD(rg,qq) (CTR + (size_t)((rg)*4+(qq))*64)
#define YPROD(rg,qq) (CTR + (size_t)(64+(rg)*4+(qq))*64)
#define YCONS(rg,qq) (CTR + (size_t)(136+(rg)*4+(qq))*64)
#define FCC(f)       (CTR + (size_t)(200+(f))*64)
#define H0R(rg) ((unsigned*)((char*)ws + O_H0R_B) + (size_t)(rg)*RGRING)
#define H1R(rg) ((unsigned*)((char*)ws + O_H1R_B) + (size_t)(rg)*RGRING)

    if (bid < 64) {
        // ======== X(rg,q): h0[t][16 rows, 128 cols] = tanh(emb@Wih0 + h0[t-1]@Whh0 + b) ========
        const int rg = bid >> 2, q = bid & 3, mb = rg * 16, qb = q * 128;
        char* Ahi = smem;           // h0[t-1] full-row A planes (16KB each)
        char* Alo = smem + 16384;
        char* Ehi = smem + 32768;   // emb A planes (2KB each)
        char* Elo = smem + 34816;
        const bf16* embhi = ws + O_EMBHI; const bf16* emblo = ws + O_EMBLO;
        const int col = qb + wv * 16 + l15;
        const float bias = bih0[col] + bhh0[col];
        const bf16* wch = ws + O_WHH0HI + (size_t)col * HSZ + quad * 8;
        const bf16* wcl = ws + O_WHH0LO + (size_t)col * HSZ + quad * 8;
        const bf16* ech = ws + O_WIH0HI + (size_t)col * EMBD + quad * 8;
        const bf16* ecl = ws + O_WIH0LO + (size_t)col * EMBD + quad * 8;
        unsigned* h0r = H0R(rg);
        const int qa = (q + 1) & 3, qb2 = (q + 2) & 3, qc = (q + 3) & 3;

        for (int i = tid * 4; i < 32768; i += 2048) *(unsigned*)(smem + i) = 0u; // h0[-1]=0
        __syncthreads();

        int scur = 0;
        for (int t = 0; t < TLEN; ++t) {
            const int sp = (scur == 0) ? 2 : scur - 1;
            // poll: 3 sibling X prods >= t; 4 Y released h0[t-3]
            const int* pp = nullptr; int nd = 0; bool act = false;
            if (wv == 0) {
                if (lane < 3) {
                    int ss = (lane == 0) ? qa : (lane == 1) ? qb2 : qc;
                    pp = XPROD(rg, ss); nd = t; act = (t > 0);
                } else if (lane < 7) {
                    pp = YCONS(rg, lane - 3); nd = t - 2; act = (t >= 3);
                }
            }
            pollv(pp, nd, act, wv);
            // stage: 3 sibling h0[t-1] quarters -> A planes; emb rows -> E planes
            if (t > 0) {
                const unsigned* sl = h0r + (size_t)sp * 8192;
                u32x4 v3[3];
                ld3x16sc(sl + qa*2048 + tid*4, sl + qb2*2048 + tid*4, sl + qc*2048 + tid*4, v3);
                awriteQ(Ahi, Alo, tid, v3[0], 0, qa * 128);
                awriteQ(Ahi, Alo, tid, v3[1], 0, qb2 * 128);
                awriteQ(Ahi, Alo, tid, v3[2], 0, qc * 128);
            }
            if (tid < 128) {
                int row = tid >> 3, oct = tid & 7;
                int xr = x[(size_t)(mb + row) * TLEN + t];
                int eoff = row * 128 + ((oct * 16) ^ ((row & 7) << 4));
                *(short8*)(Ehi + eoff) = ld8(embhi + (size_t)xr * EMBD + oct * 8);
                *(short8*)(Elo + eoff) = ld8(emblo + (size_t)xr * EMBD + oct * 8);
            }
            __syncthreads();
            // kloop: emb part (K=64) + recurrent part (K=512)
            f32x4 accA = {}, accB = {};
#pragma unroll
            for (int kc = 0; kc < 2; kc++) {
                int aoff = l15 * 128 + ((kc * 64 + quad * 16) ^ swz);
                short8 ah = *(const short8*)(Ehi + aoff);
                short8 al = *(const short8*)(Elo + aoff);
                short8 bh = ld8(ech + kc * 32);
                short8 bl = ld8(ecl + kc * 32);
                accA = MFMA(ah, bh, accA); accB = MFMA(al, bh, accB); accB = MFMA(ah, bl, accB);
            }
#pragma unroll
            for (int kc = 0; kc < 16; kc++) {
                int aoff = l15 * ASTR + ((kc * 64 + quad * 16) ^ swz);
                short8 ah = *(const short8*)(Ahi + aoff);
                short8 al = *(const short8*)(Alo + aoff);
                short8 bh = ld8(wch + kc * 32);
                short8 bl = ld8(wcl + kc * 32);
                accA = MFMA(ah, bh, accA); accB = MFMA(al, bh, accB); accB = MFMA(ah, bl, accB);
            }
            __syncthreads();                 // all A reads done before own-quarter overwrite
            // epilogue: tanh -> own LDS quarter + ring quarter
            unsigned* slot = h0r + (size_t)scur * 8192 + q * 2048;
#pragma unroll
            for (int rr = 0; rr < 4; rr++) {
                int row = quad * 4 + rr;
                float v = tanhf(accA[rr] + accB[rr] + bias);
                bf16 hb = __float2bfloat16(v);
                bf16 lb = __float2bfloat16(v - b2f(hb));
                unsigned short hu, lu;
                __builtin_memcpy(&hu, &hb, 2); __builtin_memcpy(&lu, &lb, 2);
                int loff = row * ASTR + ((col * 2) ^ ((row & 7) << 4));
                *(unsigned short*)(Ahi + loff) = hu;
                *(unsigned short*)(Alo + loff) = lu;
                st4_sc(slot + (size_t)row * 128 + wv * 16 + l15,
                       (unsigned)hu | ((unsigned)lu << 16));
            }
            asm volatile("s_waitcnt vmcnt(0)" ::: "memory");
            __syncthreads();
            if (tid == 0) st4i(XPROD(rg, q), t + 1);
            scur = (scur == 2) ? 0 : scur + 1;
        }

    } else if (bid < 128) {
        // ======== Y(rg,q): h1[t][16,128] = tanh(h1[t-1]@Whh1 + h0[t]@Wih1 + b) ========
        // Merged edges: ONE top poll (sibs + X + FC) and ONE batched 7-load round trip.
        const int rg = (bid - 64) >> 2, q = (bid - 64) & 3, qb = q * 128;
        char* A1hi = smem;            // h1[t-1] planes
        char* A1lo = smem + 16384;
        char* A2hi = smem + 32768;    // h0[t] planes
        char* A2lo = smem + 49152;
        const int col = qb + wv * 16 + l15;
        const float bias = bih1[col] + bhh1[col];
        const bf16* whh = ws + O_WHH1HI + (size_t)col * HSZ + quad * 8;
        const bf16* whl = ws + O_WHH1LO + (size_t)col * HSZ + quad * 8;
        const bf16* w1h = ws + O_WIH1HI + (size_t)col * HSZ + quad * 8;
        const bf16* w1l = ws + O_WIH1LO + (size_t)col * HSZ + quad * 8;
        unsigned* h1r = H1R(rg);
        const unsigned* h0r = H0R(rg);
        const int qa = (q + 1) & 3, qb2 = (q + 2) & 3, qc = (q + 3) & 3;
        const int f = rg >> 1;

        for (int i = tid * 4; i < 32768; i += 2048) *(unsigned*)(smem + i) = 0u; // h1[-1]=0
        __syncthreads();

        int scur = 0;
        for (int t = 0; t < TLEN; ++t) {
            const int sp = (scur == 0) ? 2 : scur - 1;
            // ONE poll: 3 sibling Y prods >= t; FC released h1[t-3]; 4 X prods >= t+1 (h0[t])
            const int* pp = nullptr; int nd = 0; bool act = false;
            if (wv == 0) {
                if (lane < 3) {
                    int ss = (lane == 0) ? qa : (lane == 1) ? qb2 : qc;
                    pp = YPROD(rg, ss); nd = t; act = (t > 0);
                } else if (lane == 3) { pp = FCC(f); nd = t - 2; act = (t >= 3); }
                else if (lane < 8)    { pp = XPROD(rg, lane - 4); nd = t + 1; act = true; }
            }
            pollv(pp, nd, act, wv);
            // ONE batched load: 3 h1-sibling quarters + 4 h0 quarters (single vmcnt wait)
            const unsigned* h0s = h0r + (size_t)scur * 8192;
            if (t > 0) {
                const unsigned* sl = h1r + (size_t)sp * 8192;
                u32x4 v7[7];
                ld7x16sc(sl + qa*2048 + tid*4, sl + qb2*2048 + tid*4, sl + qc*2048 + tid*4,
                         h0s + 0*2048 + tid*4, h0s + 1*2048 + tid*4,
                         h0s + 2*2048 + tid*4, h0s + 3*2048 + tid*4, v7);
                awriteQ(A1hi, A1lo, tid, v7[0], 0, qa * 128);
                awriteQ(A1hi, A1lo, tid, v7[1], 0, qb2 * 128);
                awriteQ(A1hi, A1lo, tid, v7[2], 0, qc * 128);
#pragma unroll
                for (int c = 0; c < 4; c++) awriteQ(A2hi, A2lo, tid, v7[3 + c], 0, c * 128);
            } else {
                u32x4 pf[4];
                pref4sc(h0s, tid, pf);
#pragma unroll
                for (int c = 0; c < 4; c++) awriteQ(A2hi, A2lo, tid, pf[c], 0, c * 128);
            }
            __syncthreads();
            if (tid == 0) st4i(YCONS(rg, q), t + 1);       // release h0[t] slot
            // kloop1: h1[t-1] @ Whh1
            f32x4 accA = {}, accB = {};
#pragma unroll
            for (int kc = 0; kc < 16; kc++) {
                int aoff = l15 * ASTR + ((kc * 64 + quad * 16) ^ swz);
                short8 ah = *(const short8*)(A1hi + aoff);
                short8 al = *(const short8*)(A1lo + aoff);
                short8 bh = ld8(whh + kc * 32);
                short8 bl = ld8(whl + kc * 32);
                accA = MFMA(ah, bh, accA); accB = MFMA(al, bh, accB); accB = MFMA(ah, bl, accB);
            }
            // kloop2: h0[t] @ Wih1 (same accumulators)
#pragma unroll
            for (int kc = 0; kc < 16; kc++) {
                int aoff = l15 * ASTR + ((kc * 64 + quad * 16) ^ swz);
                short8 ah = *(const short8*)(A2hi + aoff);
                short8 al = *(const short8*)(A2lo + aoff);
                short8 bh = ld8(w1h + kc * 32);
                short8 bl = ld8(w1l + kc * 32);
                accA = MFMA(ah, bh, accA); accB = MFMA(al, bh, accB); accB = MFMA(ah, bl, accB);
            }
            __syncthreads();                 // all waves done reading A1 before overwrite
            // epilogue
            unsigned* slot = h1r + (size_t)scur * 8192 + q * 2048;
#pragma unroll
            for (int rr = 0; rr < 4; rr++) {
                int row = quad * 4 + rr;
                float v = tanhf(accA[rr] + accB[rr] + bias);
                bf16 hb = __float2bfloat16(v);
                bf16 lb = __float2bfloat16(v - b2f(hb));
                unsigned short hu, lu;
                __builtin_memcpy(&hu, &hb, 2); __builtin_memcpy(&lu, &lb, 2);
                int loff = row * ASTR + ((col * 2) ^ ((row & 7) << 4));
                *(unsigned short*)(A1hi + loff) = hu;
                *(unsigned short*)(A1lo + loff) = lu;
                st4_sc(slot + (size_t)row * 128 + wv * 16 + l15,
                       (unsigned)hu | ((unsigned)lu << 16));
            }
            asm volatile("s_waitcnt vmcnt(0)" ::: "memory");
            __syncthreads();
            if (tid == 0) st4i(YPROD(rg, q), t + 1);
            scur = (scur == 2) ? 0 : scur + 1;
        }

    } else {
        // ======== FC(f): logits[32 rows, t, 128] = h1[t] @ Wfc + b (off critical path) ========
        const int f = bid - 128;
        char* FAhi = smem;            // 32-row planes
        char* FAlo = smem + 32768;
        const int col = wv * 16 + l15;
        const float bias = bfc[col];
        const bf16* wfh = ws + O_WFCHI + (size_t)col * HSZ + quad * 8;
        const bf16* wfl = ws + O_WFCLO + (size_t)col * HSZ + quad * 8;
        const unsigned* r1 = H1R(2 * f);
        const unsigned* r2 = H1R(2 * f + 1);

        int scur = 0;
        for (int t = 0; t < TLEN; ++t) {
            // poll: 8 Y producers (2 rgs x 4 quarters) >= t+1
            const int* pp = nullptr; int nd = 0; bool act = false;
            if (wv == 0 && lane < 8) {
                pp = YPROD(2 * f + (lane >> 2), lane & 3); nd = t + 1; act = true;
            }
            pollv(pp, nd, act, wv);
            u32x4 pf[8];
            pref8sc(r1 + (size_t)scur * 8192, r2 + (size_t)scur * 8192, tid, pf);
#pragma unroll
            for (int i = 0; i < 8; i++)
                awriteQ(FAhi, FAlo, tid, pf[i], (i >> 2) * 16, (i & 3) * 128);
            __syncthreads();
            if (tid == 0) st4i(FCC(f), t + 1);             // release h1[t] slots
            f32x4 accA[2] = {}, accB[2] = {};
#pragma unroll
            for (int kc = 0; kc < 16; kc++) {
                short8 bh = ld8(wfh + kc * 32);
                short8 bl = ld8(wfl + kc * 32);
#pragma unroll
                for (int mi = 0; mi < 2; mi++) {
                    int aoff = (mi * 16 + l15) * ASTR + ((kc * 64 + quad * 16) ^ swz);
                    short8 ah = *(const short8*)(FAhi + aoff);
                    short8 al = *(const short8*)(FAlo + aoff);
                    accA[mi] = MFMA(ah, bh, accA[mi]);
                    accB[mi] = MFMA(al, bh, accB[mi]);
                    accB[mi] = MFMA(ah, bl, accB[mi]);
                }
            }
#pragma unroll
            for (int mi = 0; mi < 2; mi++)
#pragma unroll
                for (int rr = 0; rr < 4; rr++) {
                    int row = 32 * f + mi * 16 + quad * 4 + rr;
                    out[((size_t)row * TLEN + t) * VSZ + col] = accA[mi][rr] + accB[mi][rr] + bias;
                }
            scur = (scur == 2) ? 0 : scur + 1;
        }
    }
#undef XPROD
#undef YPROD
#undef YCONS
#undef FCC
#undef H0R
#undef H1R
}

extern "C" void kernel_launch(void* const* d_in, const int* in_sizes, int n_in,
                              void* d_out, int out_size, void* d_ws, size_t ws_size,
                              hipStream_t stream) {
    const int*   x    = (const int*)d_in[0];
    const float* emb  = (const float*)d_in[1];
    const float* Wih0 = (const float*)d_in[2];
    const float* bih0 = (const float*)d_in[3];
    const float* Whh0 = (const float*)d_in[4];
    const float* bhh0 = (const float*)d_in[5];
    const float* Wih1 = (const float*)d_in[6];
    const float* bih1 = (const float*)d_in[7];
    const float* Whh1 = (const float*)d_in[8];
    const float* bhh1 = (const float*)d_in[9];
    const float* Wfc  = (const float*)d_in[10];
    const float* bfc  = (const float*)d_in[11];
    float* out = (float*)d_out;
    bf16* ws   = (bf16*)d_ws;

    const int total = 3 * HSZ * HSZ + HSZ * EMBD + VSZ * HSZ + VSZ * EMBD + CTRN * 64;
    k_prep<<<(total + 255) / 256, 256, 0, stream>>>(emb, Wih0, Whh0, Wih1, Whh1, Wfc, ws);

    k_persist<<<NBLK, 512, SMEMSZ, stream>>>(x, bih0, bhh0, bih1, bhh1, bfc, ws, out);
}